// Round 2
// baseline (26000.577 us; speedup 1.0000x reference)
//
#include <hip/hip_runtime.h>
#include <stdint.h>

#define S_ 128
#define L_ 128
#define E_ 300
#define H_ 300
#define NMAX (S_*L_)          // 16384
#define R_ 1200               // 4*H
#define D_ 600
#define XW_STRIDE ((size_t)NMAX*R_)

// ---------------- prep: prefix sums, token->(s,l) map, zero h buffers -------
__global__ void prep_kernel(const int* __restrict__ lengths, int* __restrict__ meta,
                            int* __restrict__ map, unsigned long long* __restrict__ hbuf) {
    __shared__ int offs[S_];
    int tid = threadIdx.x;
    if (tid == 0) {
        int acc = 0;
        for (int s = 0; s < S_; s++) { offs[s] = acc; acc += lengths[s]; }
        meta[0] = acc;   // N total
    }
    __syncthreads();
    for (int s = tid; s < S_; s += blockDim.x) {
        int o = offs[s], len = lengths[s];
        for (int l = 0; l < len; l++) map[o + l] = s * L_ + l;
    }
    // zero hbuf: [2 dirs][2 slots][320] u64 (tag 0 == valid h_0 = 0)
    for (int i = tid; i < 2*2*320; i += blockDim.x) hbuf[i] = 0ull;
}

// ---------------- xw = embeds @ Wih^T + (bih+bhh), both directions ----------
// grid: (NMAX/32, 10) blocks of 256. Each thread owns one output row r (w in VGPRs),
// each block covers 32 tokens; embedding row accessed via uniform (scalar) loads.
__global__ __launch_bounds__(256, 1) void xw_kernel(
    const int* __restrict__ tokens, const float* __restrict__ table,
    const float* __restrict__ Wih_f, const float* __restrict__ bih_f, const float* __restrict__ bhh_f,
    const float* __restrict__ Wih_b, const float* __restrict__ bih_b, const float* __restrict__ bhh_b,
    const int* __restrict__ meta, const int* __restrict__ map, float* __restrict__ xw) {
    const int N = meta[0];
    const int n0 = blockIdx.x * 32;
    if (n0 >= N) return;
    const int r = blockIdx.y * 256 + threadIdx.x;   // 0..2559
    const bool vr = (r < 2*R_);
    const int dir = (r >= R_) ? 1 : 0;
    const int rr = r - dir * R_;
    const float* W = dir ? Wih_b : Wih_f;
    float bias = 0.f;
    float4 w4[75];
    if (vr) {
        bias = dir ? (bih_b[rr] + bhh_b[rr]) : (bih_f[rr] + bhh_f[rr]);
        #pragma unroll
        for (int j = 0; j < 75; j++) w4[j] = *(const float4*)(W + (size_t)rr * E_ + 4*j);
    } else {
        #pragma unroll
        for (int j = 0; j < 75; j++) w4[j] = make_float4(0.f, 0.f, 0.f, 0.f);
    }
    float* xwd = xw + (size_t)dir * XW_STRIDE;
    const int iend = min(32, N - n0);
    for (int i = 0; i < iend; i++) {
        const int n = n0 + i;
        const int tok = tokens[map[n]];                  // uniform
        const float* arow = table + (size_t)tok * E_;
        float a0 = bias, a1 = 0.f, a2 = 0.f, a3 = 0.f;
        #pragma unroll
        for (int j = 0; j < 75; j++) {
            float4 a4 = *(const float4*)(arow + 4*j);    // uniform -> scalar path
            a0 = fmaf(w4[j].x, a4.x, a0);
            a1 = fmaf(w4[j].y, a4.y, a1);
            a2 = fmaf(w4[j].z, a4.z, a2);
            a3 = fmaf(w4[j].w, a4.w, a3);
        }
        if (vr) xwd[(size_t)n * R_ + rr] = (a0 + a1) + (a2 + a3);
    }
}

// ---------------- sequential BiLSTM scan -------------------------------------
__device__ __forceinline__ float sel4(int m, float a, float b, float c, float d) {
    float r = a;
    r = (m == 1) ? b : r;
    r = (m == 2) ? c : r;
    r = (m == 3) ? d : r;
    return r;
}
__device__ __forceinline__ float sigm(float x) { return 1.f / (1.f + expf(-x)); }

// grid: 10 blocks x 256 threads. block b: dir = b/5, slice = b%5 (64 h-dims each).
// lane: d = slice*64 + (tid>>2), gate = tid&3; owns Whh row (gate*300+d) in VGPRs.
// h exchanged via tagged u64 hbuf[dir][slot][dim] at AGENT scope (tag = step).
__global__ __launch_bounds__(256, 1) void scan_kernel(
    const float* __restrict__ Whh_f, const float* __restrict__ Whh_b,
    const int* __restrict__ meta, const int* __restrict__ map,
    unsigned long long* __restrict__ hbuf, const float* __restrict__ xw,
    float* __restrict__ padded) {
    const int N = meta[0];
    const int b = blockIdx.x;
    const int dir = b / 5;
    const int slice = b % 5;
    const int tid = threadIdx.x;
    const int wave = tid >> 6;
    const int lane = tid & 63;
    const int local = tid >> 2;           // 0..63
    const int gate = tid & 3;
    const int d = slice * 64 + local;     // h dim this group computes
    const bool vd = (d < H_);
    if (slice == 4 && wave == 3) return;  // no valid dims in this wave

    const float* Whh = dir ? Whh_b : Whh_f;
    const int row = gate * H_ + (vd ? d : 0);
    float4 w4[75];
    if (vd) {
        #pragma unroll
        for (int j = 0; j < 75; j++) w4[j] = *(const float4*)(Whh + (size_t)row * H_ + 4*j);
    } else {
        #pragma unroll
        for (int j = 0; j < 75; j++) w4[j] = make_float4(0.f, 0.f, 0.f, 0.f);
    }
    const float* xwd = xw + (size_t)dir * XW_STRIDE;
    unsigned long long* hb = hbuf + dir * 2 * 320;

    __shared__ float hl[4][304];
    float* hw = hl[wave];

    float c = 0.f;
    int n0 = dir ? (N - 1) : 0;
    float xw_cur = vd ? xwd[(size_t)n0 * R_ + row] : 0.f;

    for (int t = 0; t < N; t++) {
        const int n = dir ? (N - 1 - t) : t;
        // prefetch next step's xw before polling (hides HBM latency under spin)
        float xw_nxt = 0.f;
        if (vd && t + 1 < N) {
            const int nn = dir ? (N - 2 - t) : (t + 1);
            xw_nxt = xwd[(size_t)nn * R_ + row];
        }
        const int m = map[n];   // uniform scalar load

        // ---- poll h_t (tag == t) ----
        const unsigned long long* hp = hb + (size_t)(t & 1) * 320;
        const unsigned int want = (unsigned int)t;
        unsigned long long v0, v1, v2, v3, v4;
        for (;;) {
            v0 = __hip_atomic_load(hp + lane,        __ATOMIC_RELAXED, __HIP_MEMORY_SCOPE_AGENT);
            v1 = __hip_atomic_load(hp + 64  + lane,  __ATOMIC_RELAXED, __HIP_MEMORY_SCOPE_AGENT);
            v2 = __hip_atomic_load(hp + 128 + lane,  __ATOMIC_RELAXED, __HIP_MEMORY_SCOPE_AGENT);
            v3 = __hip_atomic_load(hp + 192 + lane,  __ATOMIC_RELAXED, __HIP_MEMORY_SCOPE_AGENT);
            v4 = (lane < 44) ? __hip_atomic_load(hp + 256 + lane, __ATOMIC_RELAXED, __HIP_MEMORY_SCOPE_AGENT)
                             : ((unsigned long long)want << 32);
            bool ok = ((unsigned int)(v0 >> 32) == want) &&
                      ((unsigned int)(v1 >> 32) == want) &&
                      ((unsigned int)(v2 >> 32) == want) &&
                      ((unsigned int)(v3 >> 32) == want) &&
                      ((unsigned int)(v4 >> 32) == want);
            if (ok) break;
        }
        // stage h into this wave's LDS copy
        hw[lane]        = __uint_as_float((unsigned int)v0);
        hw[64  + lane]  = __uint_as_float((unsigned int)v1);
        hw[128 + lane]  = __uint_as_float((unsigned int)v2);
        hw[192 + lane]  = __uint_as_float((unsigned int)v3);
        if (lane < 44) hw[256 + lane] = __uint_as_float((unsigned int)v4);

        // ---- dot: gate preactivation = xw + Whh_row . h ----
        float a0 = 0.f, a1 = 0.f, a2 = 0.f, a3 = 0.f;
        #pragma unroll
        for (int j = 0; j < 75; j++) {
            float4 h4 = *(const float4*)(hw + 4*j);   // broadcast read
            a0 = fmaf(w4[j].x, h4.x, a0);
            a1 = fmaf(w4[j].y, h4.y, a1);
            a2 = fmaf(w4[j].z, h4.z, a2);
            a3 = fmaf(w4[j].w, h4.w, a3);
        }
        const float acc = xw_cur + ((a0 + a1) + (a2 + a3));

        // ---- butterfly: every lane of the 4-lane group gets (i,f,g,o) ----
        const float aa  = acc;
        const float bb  = __shfl_xor(aa, 1);
        const float a2s = __shfl_xor(aa, 2);
        const float b2s = __shfl_xor(bb, 2);
        const float vi = sel4(gate ^ 0, aa, bb, a2s, b2s);
        const float vf = sel4(gate ^ 1, aa, bb, a2s, b2s);
        const float vg = sel4(gate ^ 2, aa, bb, a2s, b2s);
        const float vo = sel4(gate ^ 3, aa, bb, a2s, b2s);

        c = sigm(vf) * c + sigm(vi) * tanhf(vg);
        const float h = sigm(vo) * tanhf(c);

        if (vd && gate == 0) {
            padded[(size_t)m * D_ + dir * H_ + d] = h;
            const unsigned long long pv =
                ((unsigned long long)(unsigned int)(t + 1) << 32) |
                (unsigned long long)__float_as_uint(h);
            __hip_atomic_store(hb + (size_t)((t + 1) & 1) * 320 + d, pv,
                               __ATOMIC_RELAXED, __HIP_MEMORY_SCOPE_AGENT);
        }
        xw_cur = xw_nxt;
    }
}

// ---------------- per-sentence attention + maxpool ---------------------------
// one block per sentence; q-tiles of 16; scores/attn live in LDS.
__global__ __launch_bounds__(256) void attn_kernel(
    const int* __restrict__ lengths, const float* __restrict__ padded,
    float* __restrict__ out) {
    const int s = blockIdx.x;
    const int tid = threadIdx.x;
    const int Ls = lengths[s];
    const float* P = padded + (size_t)s * L_ * D_;
    __shared__ float sc[16][128];
    const float scale = 0.040824829046386304f;  // 1/sqrt(600)
    float vmax0 = -1e30f, vmax1 = -1e30f, vmax2 = -1e30f;

    const int nqt = (Ls + 15) / 16;
    for (int qt = 0; qt < nqt; qt++) {
        const int q0 = qt * 16;
        // ---- scores (threads 0..127 own key k = tid) ----
        if (tid < 128) {
            float acc[16];
            #pragma unroll
            for (int i = 0; i < 16; i++) acc[i] = -1e30f;
            if (tid < Ls) {
                #pragma unroll
                for (int i = 0; i < 16; i++) acc[i] = 0.f;
                const float* pk = P + (size_t)tid * D_;
                for (int e4 = 0; e4 < 150; e4++) {
                    const float4 k4 = *(const float4*)(pk + 4*e4);
                    #pragma unroll
                    for (int i = 0; i < 16; i++) {
                        const float4 q4 = *(const float4*)(P + (size_t)(q0 + i) * D_ + 4*e4);
                        acc[i] = fmaf(k4.x, q4.x, acc[i]);
                        acc[i] = fmaf(k4.y, q4.y, acc[i]);
                        acc[i] = fmaf(k4.z, q4.z, acc[i]);
                        acc[i] = fmaf(k4.w, q4.w, acc[i]);
                    }
                }
                #pragma unroll
                for (int i = 0; i < 16; i++) acc[i] *= scale;
            }
            #pragma unroll
            for (int i = 0; i < 16; i++) sc[i][tid] = acc[i];
        }
        __syncthreads();

        // ---- softmax: wave w handles rows 4w..4w+3 ----
        {
            const int w = tid >> 6, l = tid & 63;
            #pragma unroll
            for (int ii = 0; ii < 4; ii++) {
                const int i = w * 4 + ii;
                float x0 = sc[i][l], x1 = sc[i][64 + l];
                float mx = fmaxf(x0, x1);
                #pragma unroll
                for (int off = 32; off; off >>= 1) mx = fmaxf(mx, __shfl_xor(mx, off));
                float e0 = expf(x0 - mx), e1 = expf(x1 - mx);
                float sm = e0 + e1;
                #pragma unroll
                for (int off = 32; off; off >>= 1) sm += __shfl_xor(sm, off);
                const float inv = 1.f / sm;
                sc[i][l] = e0 * inv;
                sc[i][64 + l] = e1 * inv;
            }
        }
        __syncthreads();

        // ---- ctx = attn @ P, fold into running max over valid queries ----
        #pragma unroll
        for (int j = 0; j < 3; j++) {
            const int dd = j * 256 + tid;
            if (dd < D_) {
                float ca[16];
                #pragma unroll
                for (int i = 0; i < 16; i++) ca[i] = 0.f;
                for (int k4 = 0; k4 < 32; k4++) {
                    const float p0 = P[(size_t)(4*k4 + 0) * D_ + dd];
                    const float p1 = P[(size_t)(4*k4 + 1) * D_ + dd];
                    const float p2 = P[(size_t)(4*k4 + 2) * D_ + dd];
                    const float p3 = P[(size_t)(4*k4 + 3) * D_ + dd];
                    #pragma unroll
                    for (int i = 0; i < 16; i++) {
                        const float4 pr = *(const float4*)(&sc[i][4*k4]);
                        ca[i] = fmaf(pr.x, p0, ca[i]);
                        ca[i] = fmaf(pr.y, p1, ca[i]);
                        ca[i] = fmaf(pr.z, p2, ca[i]);
                        ca[i] = fmaf(pr.w, p3, ca[i]);
                    }
                }
                float vm = (j == 0) ? vmax0 : (j == 1) ? vmax1 : vmax2;
                #pragma unroll
                for (int i = 0; i < 16; i++)
                    if (q0 + i < Ls) vm = fmaxf(vm, ca[i]);
                if (j == 0) vmax0 = vm; else if (j == 1) vmax1 = vm; else vmax2 = vm;
            }
        }
        __syncthreads();
    }
    if (tid < D_)        out[(size_t)s * D_ + tid] = vmax0;
    if (256 + tid < D_)  out[(size_t)s * D_ + 256 + tid] = vmax1;
    if (512 + tid < D_)  out[(size_t)s * D_ + 512 + tid] = vmax2;
}

// ---------------- launcher ----------------------------------------------------
extern "C" void kernel_launch(void* const* d_in, const int* in_sizes, int n_in,
                              void* d_out, int out_size, void* d_ws, size_t ws_size,
                              hipStream_t stream) {
    const int*   tokens  = (const int*)d_in[0];
    const int*   lengths = (const int*)d_in[1];
    const float* table   = (const float*)d_in[2];
    const float* Wih_f   = (const float*)d_in[3];
    const float* Whh_f   = (const float*)d_in[4];
    const float* bih_f   = (const float*)d_in[5];
    const float* bhh_f   = (const float*)d_in[6];
    const float* Wih_b   = (const float*)d_in[7];
    const float* Whh_b   = (const float*)d_in[8];
    const float* bih_b   = (const float*)d_in[9];
    const float* bhh_b   = (const float*)d_in[10];
    float* out = (float*)d_out;

    char* ws = (char*)d_ws;
    int* meta                 = (int*)(ws + 0);                       // 256 B
    int* map                  = (int*)(ws + 256);                     // 64 KB
    unsigned long long* hbuf  = (unsigned long long*)(ws + 256 + 65536);        // 10240 B
    float* xw                 = (float*)(ws + 256 + 65536 + 10240);   // 2*16384*1200 f32
    float* padded             = (float*)(ws + 256 + 65536 + 10240 + (size_t)2*NMAX*R_*4);

    prep_kernel<<<1, 256, 0, stream>>>(lengths, meta, map, hbuf);
    xw_kernel<<<dim3(NMAX/32, 10), 256, 0, stream>>>(tokens, table,
        Wih_f, bih_f, bhh_f, Wih_b, bih_b, bhh_b, meta, map, xw);
    scan_kernel<<<10, 256, 0, stream>>>(Whh_f, Whh_b, meta, map, hbuf, xw, padded);
    attn_kernel<<<S_, 256, 0, stream>>>(lengths, padded, out);
}

// Round 3
// 19733.205 us; speedup vs baseline: 1.3176x; 1.3176x over previous
//
#include <hip/hip_runtime.h>
#include <stdint.h>

#define S_ 128
#define L_ 128
#define E_ 300
#define H_ 300
#define NMAX (S_*L_)          // 16384
#define R_ 1200               // 4*H
#define D_ 600
#define XW_STRIDE ((size_t)NMAX*R_)

// ---------------- prep: prefix sums, token->(s,l) map, zero h buffers -------
__global__ void prep_kernel(const int* __restrict__ lengths, int* __restrict__ meta,
                            int* __restrict__ map, unsigned long long* __restrict__ hbuf) {
    __shared__ int offs[S_];
    int tid = threadIdx.x;
    if (tid == 0) {
        int acc = 0;
        for (int s = 0; s < S_; s++) { offs[s] = acc; acc += lengths[s]; }
        meta[0] = acc;   // N total
    }
    __syncthreads();
    for (int s = tid; s < S_; s += blockDim.x) {
        int o = offs[s], len = lengths[s];
        for (int l = 0; l < len; l++) map[o + l] = s * L_ + l;
    }
    // zero hbuf: [2 dirs][2 slots][320] u64 (tag 0 == valid h_0 = 0)
    for (int i = tid; i < 2*2*320; i += blockDim.x) hbuf[i] = 0ull;
}

// ---------------- xw = embeds @ Wih^T + (bih+bhh), both directions ----------
__global__ __launch_bounds__(256, 1) void xw_kernel(
    const int* __restrict__ tokens, const float* __restrict__ table,
    const float* __restrict__ Wih_f, const float* __restrict__ bih_f, const float* __restrict__ bhh_f,
    const float* __restrict__ Wih_b, const float* __restrict__ bih_b, const float* __restrict__ bhh_b,
    const int* __restrict__ meta, const int* __restrict__ map, float* __restrict__ xw) {
    const int N = meta[0];
    const int n0 = blockIdx.x * 32;
    if (n0 >= N) return;
    const int r = blockIdx.y * 256 + threadIdx.x;   // 0..2559
    const bool vr = (r < 2*R_);
    const int dir = (r >= R_) ? 1 : 0;
    const int rr = r - dir * R_;
    const float* W = dir ? Wih_b : Wih_f;
    float bias = 0.f;
    float4 w4[75];
    if (vr) {
        bias = dir ? (bih_b[rr] + bhh_b[rr]) : (bih_f[rr] + bhh_f[rr]);
        #pragma unroll
        for (int j = 0; j < 75; j++) w4[j] = *(const float4*)(W + (size_t)rr * E_ + 4*j);
    } else {
        #pragma unroll
        for (int j = 0; j < 75; j++) w4[j] = make_float4(0.f, 0.f, 0.f, 0.f);
    }
    float* xwd = xw + (size_t)dir * XW_STRIDE;
    const int iend = min(32, N - n0);
    for (int i = 0; i < iend; i++) {
        const int n = n0 + i;
        const int tok = tokens[map[n]];                  // uniform
        const float* arow = table + (size_t)tok * E_;
        float a0 = bias, a1 = 0.f, a2 = 0.f, a3 = 0.f;
        #pragma unroll
        for (int j = 0; j < 75; j++) {
            float4 a4 = *(const float4*)(arow + 4*j);    // uniform -> scalar path
            a0 = fmaf(w4[j].x, a4.x, a0);
            a1 = fmaf(w4[j].y, a4.y, a1);
            a2 = fmaf(w4[j].z, a4.z, a2);
            a3 = fmaf(w4[j].w, a4.w, a3);
        }
        if (vr) xwd[(size_t)n * R_ + rr] = (a0 + a1) + (a2 + a3);
    }
}

// ---------------- sequential BiLSTM scan -------------------------------------
__device__ __forceinline__ float sel4(int m, float a, float b, float c, float d) {
    float r = a;
    r = (m == 1) ? b : r;
    r = (m == 2) ? c : r;
    r = (m == 3) ? d : r;
    return r;
}
// fast activations (v_exp_f32 + v_rcp_f32); NaN-free at +/-inf
__device__ __forceinline__ float sigm(float x) {
    return __builtin_amdgcn_rcpf(1.f + __expf(-x));
}
__device__ __forceinline__ float tanh_fast(float x) {
    return 1.f - 2.f * __builtin_amdgcn_rcpf(1.f + __expf(2.f * x));
}

// grid: 20 blocks x 256 threads. block b: dir = b/10, blk = b%10 (32 h-dims each).
// thread: pair = tid>>1 owns one Whh row (dim = 32*blk + (pair>>2), gate = pair&3);
// half = tid&1 owns half the 300-wide dot (152 weights in VGPRs -> register-resident).
// h exchanged via tagged u64 hbuf[dir][slot][dim] at AGENT scope (tag = step).
__global__ __launch_bounds__(256, 1) void scan_kernel(
    const float* __restrict__ Whh_f, const float* __restrict__ Whh_b,
    const int* __restrict__ meta, const int* __restrict__ map,
    unsigned long long* __restrict__ hbuf, const float* __restrict__ xw,
    float* __restrict__ padded) {
    const int N = meta[0];
    const int b = blockIdx.x;
    const int dir = b / 10;
    const int blk = b % 10;
    const int tid = threadIdx.x;
    const int wave = tid >> 6;
    const int lane = tid & 63;
    const int pair = tid >> 1;            // 0..127
    const int half = tid & 1;
    const int gate = pair & 3;
    const int d = 32 * blk + (pair >> 2); // h dim this row-group computes
    const bool vd = (d < H_);
    if (32 * blk + 8 * wave >= H_) return;   // wave has no valid dims

    const float* Whh = dir ? Whh_b : Whh_f;
    const int row = gate * H_ + (vd ? d : 0);
    const int cbase = half ? 148 : 0;     // half0: cols 0..147(+pad), half1: 148..299
    float4 w4[38];
    if (vd) {
        const float* wr = Whh + (size_t)row * H_ + cbase;
        #pragma unroll
        for (int j = 0; j < 38; j++) w4[j] = *(const float4*)(wr + 4*j);
        if (half == 0) w4[37] = make_float4(0.f, 0.f, 0.f, 0.f);  // pad
    } else {
        #pragma unroll
        for (int j = 0; j < 38; j++) w4[j] = make_float4(0.f, 0.f, 0.f, 0.f);
    }
    const float* xwd = xw + (size_t)dir * XW_STRIDE;
    unsigned long long* hb = hbuf + dir * 2 * 320;

    __shared__ float hl[4][304];
    float* hw = hl[wave];

    float c = 0.f;
    int n0 = dir ? (N - 1) : 0;
    float xw_cur = vd ? xwd[(size_t)n0 * R_ + row] : 0.f;

    for (int t = 0; t < N; t++) {
        const int n = dir ? (N - 1 - t) : t;
        // prefetch next step's xw before polling (hides HBM latency under spin)
        float xw_nxt = 0.f;
        if (vd && t + 1 < N) {
            const int nn = dir ? (N - 2 - t) : (t + 1);
            xw_nxt = xwd[(size_t)nn * R_ + row];
        }
        const int m = map[n];   // uniform scalar load

        // ---- poll h_t (tag == t) ----
        const unsigned long long* hp = hb + (size_t)(t & 1) * 320;
        const unsigned int want = (unsigned int)t;
        unsigned long long v0, v1, v2, v3, v4;
        for (;;) {
            v0 = __hip_atomic_load(hp + lane,        __ATOMIC_RELAXED, __HIP_MEMORY_SCOPE_AGENT);
            v1 = __hip_atomic_load(hp + 64  + lane,  __ATOMIC_RELAXED, __HIP_MEMORY_SCOPE_AGENT);
            v2 = __hip_atomic_load(hp + 128 + lane,  __ATOMIC_RELAXED, __HIP_MEMORY_SCOPE_AGENT);
            v3 = __hip_atomic_load(hp + 192 + lane,  __ATOMIC_RELAXED, __HIP_MEMORY_SCOPE_AGENT);
            v4 = (lane < 44) ? __hip_atomic_load(hp + 256 + lane, __ATOMIC_RELAXED, __HIP_MEMORY_SCOPE_AGENT)
                             : ((unsigned long long)want << 32);
            bool ok = ((unsigned int)(v0 >> 32) == want) &&
                      ((unsigned int)(v1 >> 32) == want) &&
                      ((unsigned int)(v2 >> 32) == want) &&
                      ((unsigned int)(v3 >> 32) == want) &&
                      ((unsigned int)(v4 >> 32) == want);
            if (ok) break;
        }
        // stage h into this wave's LDS copy
        hw[lane]        = __uint_as_float((unsigned int)v0);
        hw[64  + lane]  = __uint_as_float((unsigned int)v1);
        hw[128 + lane]  = __uint_as_float((unsigned int)v2);
        hw[192 + lane]  = __uint_as_float((unsigned int)v3);
        if (lane < 44) hw[256 + lane] = __uint_as_float((unsigned int)v4);

        // ---- half-dot: 38 float4 FMAs from registers (uniform control flow) ----
        const float* hbase = hw + cbase;
        float a0 = 0.f, a1 = 0.f, a2 = 0.f, a3 = 0.f;
        #pragma unroll
        for (int j = 0; j < 38; j++) {
            float4 h4 = *(const float4*)(hbase + 4*j);   // 2 addrs/wave -> broadcast
            a0 = fmaf(w4[j].x, h4.x, a0);
            a1 = fmaf(w4[j].y, h4.y, a1);
            a2 = fmaf(w4[j].z, h4.z, a2);
            a3 = fmaf(w4[j].w, h4.w, a3);
        }
        float sum = (a0 + a1) + (a2 + a3);
        sum += __shfl_xor(sum, 1);                 // combine halves
        const float acc = xw_cur + sum;

        // ---- butterfly: gate bits are tid bits 1..2 ----
        const float aa = acc;
        const float bb = __shfl_xor(acc, 2);
        const float cc = __shfl_xor(acc, 4);
        const float dd = __shfl_xor(bb, 4);
        const float vi = sel4(gate,     aa, bb, cc, dd);
        const float vf = sel4(gate ^ 1, aa, bb, cc, dd);
        const float vg = sel4(gate ^ 2, aa, bb, cc, dd);
        const float vo = sel4(gate ^ 3, aa, bb, cc, dd);

        c = sigm(vf) * c + sigm(vi) * tanh_fast(vg);
        const float h = sigm(vo) * tanh_fast(c);

        if (vd && gate == 0 && half == 0) {
            padded[(size_t)m * D_ + dir * H_ + d] = h;
            const unsigned long long pv =
                ((unsigned long long)(unsigned int)(t + 1) << 32) |
                (unsigned long long)__float_as_uint(h);
            __hip_atomic_store(hb + (size_t)((t + 1) & 1) * 320 + d, pv,
                               __ATOMIC_RELAXED, __HIP_MEMORY_SCOPE_AGENT);
        }
        xw_cur = xw_nxt;
    }
}

// ---------------- per-sentence attention + maxpool ---------------------------
__global__ __launch_bounds__(256) void attn_kernel(
    const int* __restrict__ lengths, const float* __restrict__ padded,
    float* __restrict__ out) {
    const int s = blockIdx.x;
    const int tid = threadIdx.x;
    const int Ls = lengths[s];
    const float* P = padded + (size_t)s * L_ * D_;
    __shared__ float sc[16][128];
    const float scale = 0.040824829046386304f;  // 1/sqrt(600)
    float vmax0 = -1e30f, vmax1 = -1e30f, vmax2 = -1e30f;

    const int nqt = (Ls + 15) / 16;
    for (int qt = 0; qt < nqt; qt++) {
        const int q0 = qt * 16;
        if (tid < 128) {
            float acc[16];
            #pragma unroll
            for (int i = 0; i < 16; i++) acc[i] = -1e30f;
            if (tid < Ls) {
                #pragma unroll
                for (int i = 0; i < 16; i++) acc[i] = 0.f;
                const float* pk = P + (size_t)tid * D_;
                for (int e4 = 0; e4 < 150; e4++) {
                    const float4 k4 = *(const float4*)(pk + 4*e4);
                    #pragma unroll
                    for (int i = 0; i < 16; i++) {
                        const float4 q4 = *(const float4*)(P + (size_t)(q0 + i) * D_ + 4*e4);
                        acc[i] = fmaf(k4.x, q4.x, acc[i]);
                        acc[i] = fmaf(k4.y, q4.y, acc[i]);
                        acc[i] = fmaf(k4.z, q4.z, acc[i]);
                        acc[i] = fmaf(k4.w, q4.w, acc[i]);
                    }
                }
                #pragma unroll
                for (int i = 0; i < 16; i++) acc[i] *= scale;
            }
            #pragma unroll
            for (int i = 0; i < 16; i++) sc[i][tid] = acc[i];
        }
        __syncthreads();

        {
            const int w = tid >> 6, l = tid & 63;
            #pragma unroll
            for (int ii = 0; ii < 4; ii++) {
                const int i = w * 4 + ii;
                float x0 = sc[i][l], x1 = sc[i][64 + l];
                float mx = fmaxf(x0, x1);
                #pragma unroll
                for (int off = 32; off; off >>= 1) mx = fmaxf(mx, __shfl_xor(mx, off));
                float e0 = expf(x0 - mx), e1 = expf(x1 - mx);
                float sm = e0 + e1;
                #pragma unroll
                for (int off = 32; off; off >>= 1) sm += __shfl_xor(sm, off);
                const float inv = 1.f / sm;
                sc[i][l] = e0 * inv;
                sc[i][64 + l] = e1 * inv;
            }
        }
        __syncthreads();

        #pragma unroll
        for (int j = 0; j < 3; j++) {
            const int dd = j * 256 + tid;
            if (dd < D_) {
                float ca[16];
                #pragma unroll
                for (int i = 0; i < 16; i++) ca[i] = 0.f;
                for (int k4 = 0; k4 < 32; k4++) {
                    const float p0 = P[(size_t)(4*k4 + 0) * D_ + dd];
                    const float p1 = P[(size_t)(4*k4 + 1) * D_ + dd];
                    const float p2 = P[(size_t)(4*k4 + 2) * D_ + dd];
                    const float p3 = P[(size_t)(4*k4 + 3) * D_ + dd];
                    #pragma unroll
                    for (int i = 0; i < 16; i++) {
                        const float4 pr = *(const float4*)(&sc[i][4*k4]);
                        ca[i] = fmaf(pr.x, p0, ca[i]);
                        ca[i] = fmaf(pr.y, p1, ca[i]);
                        ca[i] = fmaf(pr.z, p2, ca[i]);
                        ca[i] = fmaf(pr.w, p3, ca[i]);
                    }
                }
                float vm = (j == 0) ? vmax0 : (j == 1) ? vmax1 : vmax2;
                #pragma unroll
                for (int i = 0; i < 16; i++)
                    if (q0 + i < Ls) vm = fmaxf(vm, ca[i]);
                if (j == 0) vmax0 = vm; else if (j == 1) vmax1 = vm; else vmax2 = vm;
            }
        }
        __syncthreads();
    }
    if (tid < D_)        out[(size_t)s * D_ + tid] = vmax0;
    if (256 + tid < D_)  out[(size_t)s * D_ + 256 + tid] = vmax1;
    if (512 + tid < D_)  out[(size_t)s * D_ + 512 + tid] = vmax2;
}

// ---------------- launcher ----------------------------------------------------
extern "C" void kernel_launch(void* const* d_in, const int* in_sizes, int n_in,
                              void* d_out, int out_size, void* d_ws, size_t ws_size,
                              hipStream_t stream) {
    const int*   tokens  = (const int*)d_in[0];
    const int*   lengths = (const int*)d_in[1];
    const float* table   = (const float*)d_in[2];
    const float* Wih_f   = (const float*)d_in[3];
    const float* Whh_f   = (const float*)d_in[4];
    const float* bih_f   = (const float*)d_in[5];
    const float* bhh_f   = (const float*)d_in[6];
    const float* Wih_b   = (const float*)d_in[7];
    const float* Whh_b   = (const float*)d_in[8];
    const float* bih_b   = (const float*)d_in[9];
    const float* bhh_b   = (const float*)d_in[10];
    float* out = (float*)d_out;

    char* ws = (char*)d_ws;
    int* meta                 = (int*)(ws + 0);                       // 256 B
    int* map                  = (int*)(ws + 256);                     // 64 KB
    unsigned long long* hbuf  = (unsigned long long*)(ws + 256 + 65536);        // 10240 B
    float* xw                 = (float*)(ws + 256 + 65536 + 10240);   // 2*16384*1200 f32
    float* padded             = (float*)(ws + 256 + 65536 + 10240 + (size_t)2*NMAX*R_*4);

    prep_kernel<<<1, 256, 0, stream>>>(lengths, meta, map, hbuf);
    xw_kernel<<<dim3(NMAX/32, 10), 256, 0, stream>>>(tokens, table,
        Wih_f, bih_f, bhh_f, Wih_b, bih_b, bhh_b, meta, map, xw);
    scan_kernel<<<20, 256, 0, stream>>>(Whh_f, Whh_b, meta, map, hbuf, xw, padded);
    attn_kernel<<<S_, 256, 0, stream>>>(lengths, padded, out);
}